// Round 6
// baseline (121.672 us; speedup 1.0000x reference)
//
#include <hip/hip_runtime.h>
#include <math.h>

// Problem shape (fixed by setup_inputs): x [B,T,D] fp32, w [D,1], b [1]
#define B  16
#define T  2048
#define D  512
#define NS 64            // segments along T
#define L  32            // rows per segment
#define D4 128           // float4 per row

__device__ __forceinline__ void fma4(float4& a, float s, const float4& v) {
    a.x = fmaf(s, v.x, a.x); a.y = fmaf(s, v.y, a.y);
    a.z = fmaf(s, v.z, a.z); a.w = fmaf(s, v.w, a.w);
}

// ---------------------------------------------------------------------------
// Single-pass decoupled-lookback, x-tile staged in LDS (compiler cannot
// rematerialize LDS -> no phase-3 global re-read, unlike R3/R5).
// 1024 blocks (ticketed), 256 thr = 4 waves; thread view for vector work is
// (half = tid>>7, col = tid&127): half h owns rows h*16..h*16+15 of its col.
// ---------------------------------------------------------------------------
__global__ __launch_bounds__(256) void fused_lds(
        const float* __restrict__ x, const float* __restrict__ w,
        const float* __restrict__ bias,
        int* __restrict__ counter, int* __restrict__ flags,
        float* __restrict__ m_g, float* __restrict__ q_g,
        float* __restrict__ V, float* __restrict__ out) {
    const int tid = threadIdx.x, lane = tid & 63, wv = tid >> 6;
    const int half = tid >> 7, col = tid & 127;

    __shared__ float4 tile4[L][D4];     // 64 KB: the x tile
    __shared__ float4 vlo[D4];          // 2 KB: lo-half V partial
    __shared__ float4 seedbuf[2][D4];   // 4 KB
    __shared__ float s_sh[L], e_sh[L], sc_sh[NS], wl[L], il[L];
    __shared__ float sck_sh;
    __shared__ int vb_sh;

    if (tid == 0) vb_sh = atomicAdd(counter, 1);   // ticket = start order
    __syncthreads();
    const int blk = vb_sh;
    const int b = blk >> 6, k = blk & (NS - 1);
    const int t0 = k * L;

    // ---- stage x tile -> LDS (x read from HBM exactly once) ----
    const float4* xg = (const float4*)x + ((size_t)b * T + t0) * D4;
    float4 stg[16];
#pragma unroll
    for (int it = 0; it < 16; ++it) stg[it] = xg[it * 256 + tid];
    const float4 w0 = ((const float4*)w)[lane];
    const float4 w1 = ((const float4*)w)[lane + 64];
#pragma unroll
    for (int it = 0; it < 16; ++it) ((float4*)tile4)[it * 256 + tid] = stg[it];
    __syncthreads();

    // ---- dots: wave wv handles rows wv*8..+7, lane-split + shuffle ----
#pragma unroll
    for (int r = 0; r < 8; ++r) {
        const int row = wv * 8 + r;
        const float4 xa = tile4[row][lane];
        const float4 xb = tile4[row][lane + 64];
        float d = xa.x * w0.x + xa.y * w0.y + xa.z * w0.z + xa.w * w0.w +
                  xb.x * w1.x + xb.y * w1.y + xb.z * w1.z + xb.w * w1.w;
#pragma unroll
        for (int off = 32; off > 0; off >>= 1) d += __shfl_xor(d, off);
        if (lane == 0) s_sh[row] = d + bias[0];
    }
    __syncthreads();

    float mk = -1e30f;
#pragma unroll
    for (int j = 0; j < L; ++j) mk = fmaxf(mk, s_sh[j]);

    float q = 0.f;
    if (wv == 0) {
        const float e = (lane < L) ? __expf(s_sh[lane] - mk) : 0.f;
        if (lane < L) e_sh[lane] = e;
        q = e;
#pragma unroll
        for (int off = 32; off > 0; off >>= 1) q += __shfl_xor(q, off);
    }
    __syncthreads();

    // ---- V column-wise: half h sums its 16 rows for its col ----
    float4 acc = {0.f, 0.f, 0.f, 0.f};
    const int r0 = half * 16;
#pragma unroll
    for (int j = 0; j < 16; ++j) fma4(acc, e_sh[r0 + j], tile4[r0 + j][col]);
    if (half == 0) vlo[col] = acc;
    __syncthreads();
    if (half == 1) {
        const float4 lo = vlo[col];
        float4 vf;
        vf.x = lo.x + acc.x; vf.y = lo.y + acc.y;
        vf.z = lo.z + acc.z; vf.w = lo.w + acc.w;
        ((float4*)V)[(size_t)blk * D4 + col] = vf;
    }
    if (tid == 0) { m_g[blk] = mk; q_g[blk] = q; }
    __syncthreads();               // vmcnt(0) drain before barrier: V,m,q issued
    if (tid == 0) {
        __threadfence();           // flush to coherence point (agent scope)
        __hip_atomic_store(&flags[blk], 1, __ATOMIC_RELEASE, __HIP_MEMORY_SCOPE_AGENT);
    }

    // ---- lookback: wave 0 polls predecessors (publish precedes wait) ----
    if (wv == 0) {
        float mj = -1e30f, qj = 0.f;
        if (lane < k) {
            while (__hip_atomic_load(&flags[b * NS + lane], __ATOMIC_ACQUIRE,
                                     __HIP_MEMORY_SCOPE_AGENT) == 0)
                __builtin_amdgcn_s_sleep(4);
            mj = m_g[b * NS + lane];
            qj = q_g[b * NS + lane];
        }
        float REF = fmaxf(mk, mj);
#pragma unroll
        for (int off = 32; off > 0; off >>= 1) REF = fmaxf(REF, __shfl_xor(REF, off));
        const float scj = (lane < k) ? __expf(mj - REF) : 0.f;
        sc_sh[lane] = scj;
        float qp = scj * qj;
#pragma unroll
        for (int off = 32; off > 0; off >>= 1) qp += __shfl_xor(qp, off);
        const float sck = __expf(mk - REF);
        if (lane == 0) sck_sh = sck;
        const float e_j = (lane < L) ? e_sh[lane] : 0.f;
        float ce = e_j;
#pragma unroll
        for (int off = 1; off < 32; off <<= 1) {
            const float t = __shfl_up(ce, off);
            if (lane >= off) ce += t;
        }
        if (lane < L) {
            wl[lane] = sck * e_j;                 // global-scale row weight
            il[lane] = 1.0f / fmaf(sck, ce, qp);  // 1 / running denominator
        }
    }
    __syncthreads();

    // ---- seed per column: sum_{kp<k} sc_kp * V[b,kp,col] (V is L2-hot) ----
    float4 sacc = {0.f, 0.f, 0.f, 0.f};
    const float4* Vb = (const float4*)V + (size_t)(b * NS) * D4;
    for (int kp = half; kp < k; kp += 2)
        fma4(sacc, sc_sh[kp], Vb[(size_t)kp * D4 + col]);
    seedbuf[half][col] = sacc;
    __syncthreads();
    float4 seed;
    {
        const float4 s0 = seedbuf[0][col], s1 = seedbuf[1][col];
        seed.x = s0.x + s1.x; seed.y = s0.y + s1.y;
        seed.z = s0.z + s1.z; seed.w = s0.w + s1.w;
    }
    if (half) fma4(seed, sck_sh, vlo[col]);   // hi half: + sck * (rows 0..15)

    // ---- seeded column scan from LDS, write out ----
    float4* outb = (float4*)out + (size_t)b * T * D4;
    if (k == 0 && half == 0) outb[col] = tile4[0][col];   // out[b,0,:]=x[b,0,:]
#pragma unroll
    for (int j = 0; j < 16; ++j) {
        const int jj = r0 + j;
        fma4(seed, wl[jj], tile4[jj][col]);
        const int t = t0 + jj;
        if (t < T - 1) {
            const float idn = il[jj];
            float4 o;
            o.x = seed.x * idn; o.y = seed.y * idn;
            o.z = seed.z * idn; o.w = seed.w * idn;
            outb[(size_t)(t + 1) * D4 + col] = o;
        }
    }
}

// ---------------------------------------------------------------------------
extern "C" void kernel_launch(void* const* d_in, const int* in_sizes, int n_in,
                              void* d_out, int out_size, void* d_ws, size_t ws_size,
                              hipStream_t stream) {
    const float* x    = (const float*)d_in[0];
    const float* w    = (const float*)d_in[1];
    const float* bias = (const float*)d_in[2];
    float* out = (float*)d_out;

    // ws layout: [0,8192) bytes: counter (int @0) + flags (int[B*NS] @256B)
    //            then floats: m[B*NS] | q[B*NS] | V[B*NS*D]
    int*   counter = (int*)d_ws;
    int*   flags   = counter + 64;
    float* m_g     = (float*)((char*)d_ws + 8192);
    float* q_g     = m_g + (size_t)B * NS;
    float* V       = q_g + (size_t)B * NS;

    hipMemsetAsync(d_ws, 0, 8192, stream);   // reset ticket + flags each call
    fused_lds<<<B * NS, 256, 0, stream>>>(x, w, bias, counter, flags,
                                          m_g, q_g, V, out);
}

// Round 7
// 49.186 us; speedup vs baseline: 2.4737x; 2.4737x over previous
//
#include <hip/hip_runtime.h>
#include <math.h>

// Problem shape (fixed by setup_inputs): x [B,T,D] fp32, w [D,1], b [1]
#define B  16
#define T  2048
#define D  512
#define NS 64            // segments along T
#define L  32            // rows per segment
#define D4 128           // float4 per row

__device__ __forceinline__ void fma4(float4& a, float s, const float4& v) {
    a.x = fmaf(s, v.x, a.x); a.y = fmaf(s, v.y, a.y);
    a.z = fmaf(s, v.z, a.z); a.w = fmaf(s, v.w, a.w);
}

// ---------------------------------------------------------------------------
// K1: per (batch, segment) block, 256 thr = 4 waves, 8 rows/wave in regs.
//   s_j = dot(x_j,w)+bias ; m_k ; e_j = exp(s_j-m_k) ; q_k = sum e_j
//   denloc[t] = prefix_j<=t e_j ; V_k = sum e_j x_j
//   ctx[b,t+1] = local prefix sum e_j x_j  -> written UNNORMALIZED into out
//   (x read from HBM exactly once; out acts as the ctx scratch)
// ---------------------------------------------------------------------------
__global__ __launch_bounds__(256) void seg_scan_kernel(
        const float* __restrict__ x, const float* __restrict__ w,
        const float* __restrict__ bias,
        float* __restrict__ m_g, float* __restrict__ q_g,
        float* __restrict__ V, float* __restrict__ denloc,
        float* __restrict__ out) {
    const int b = blockIdx.x >> 6, k = blockIdx.x & (NS - 1);
    const int t0 = k * L;
    const int tid = threadIdx.x, lane = tid & 63, wv = tid >> 6;

    const float4* x4 = (const float4*)x + ((size_t)b * T + t0) * D4;
    const float4* w4 = (const float4*)w;
    const float4 w0 = w4[lane], w1 = w4[lane + 64];

    float4 xr0[8], xr1[8];
    float dots[8];
#pragma unroll
    for (int r = 0; r < 8; ++r) {
        const int j = wv * 8 + r;
        xr0[r] = x4[(size_t)j * D4 + lane];
        xr1[r] = x4[(size_t)j * D4 + lane + 64];
        dots[r] = xr0[r].x * w0.x + xr0[r].y * w0.y + xr0[r].z * w0.z + xr0[r].w * w0.w +
                  xr1[r].x * w1.x + xr1[r].y * w1.y + xr1[r].z * w1.z + xr1[r].w * w1.w;
    }

    __shared__ float s_sh[L], e_sh[L];
    __shared__ float accbuf[4][D];

#pragma unroll
    for (int r = 0; r < 8; ++r) {
        float d = dots[r];
#pragma unroll
        for (int off = 32; off > 0; off >>= 1) d += __shfl_xor(d, off);
        if (lane == 0) s_sh[wv * 8 + r] = d + bias[0];
    }
    __syncthreads();

    float mk = -1e30f;
#pragma unroll
    for (int j = 0; j < L; ++j) mk = fmaxf(mk, s_sh[j]);

    if (wv == 0) {
        const float e = (lane < L) ? __expf(s_sh[lane] - mk) : 0.f;
        if (lane < L) e_sh[lane] = e;
        float q = e;
#pragma unroll
        for (int off = 32; off > 0; off >>= 1) q += __shfl_xor(q, off);
        float ce = e;                       // inclusive prefix of e over rows
#pragma unroll
        for (int off = 1; off < 32; off <<= 1) {
            const float t = __shfl_up(ce, off);
            if (lane >= off) ce += t;
        }
        if (lane < L) denloc[(size_t)b * T + t0 + lane] = ce;
        if (lane == 0) { m_g[b * NS + k] = mk; q_g[b * NS + k] = q; }
    }
    __syncthreads();

    // per-wave partial of its 8 rows
    float er[8];
    float4 t0v = {0.f, 0.f, 0.f, 0.f}, t1v = {0.f, 0.f, 0.f, 0.f};
#pragma unroll
    for (int r = 0; r < 8; ++r) {
        er[r] = e_sh[wv * 8 + r];
        fma4(t0v, er[r], xr0[r]); fma4(t1v, er[r], xr1[r]);
    }
    ((float4*)accbuf[wv])[lane]      = t0v;
    ((float4*)accbuf[wv])[lane + 64] = t1v;
    __syncthreads();

    if (tid < 128) {                        // V_k = sum of the 4 wave partials
        const float4 r0 = ((float4*)accbuf[0])[tid];
        const float4 r1 = ((float4*)accbuf[1])[tid];
        const float4 r2 = ((float4*)accbuf[2])[tid];
        const float4 r3 = ((float4*)accbuf[3])[tid];
        float4 rr;
        rr.x = (r0.x + r1.x) + (r2.x + r3.x);
        rr.y = (r0.y + r1.y) + (r2.y + r3.y);
        rr.z = (r0.z + r1.z) + (r2.z + r3.z);
        rr.w = (r0.w + r1.w) + (r2.w + r3.w);
        ((float4*)V)[((size_t)b * NS + k) * D4 + tid] = rr;
    }

    float4 p0 = {0.f, 0.f, 0.f, 0.f}, p1 = {0.f, 0.f, 0.f, 0.f};
    for (int w2 = 0; w2 < wv; ++w2) {       // wave-uniform lookback in LDS
        const float4 c0 = ((float4*)accbuf[w2])[lane];
        const float4 c1 = ((float4*)accbuf[w2])[lane + 64];
        p0.x += c0.x; p0.y += c0.y; p0.z += c0.z; p0.w += c0.w;
        p1.x += c1.x; p1.y += c1.y; p1.z += c1.z; p1.w += c1.w;
    }

    float4* outb = (float4*)out + (size_t)b * T * D4;
    if (k == 0 && wv == 0) {                // out[b,0,:] = x[b,0,:] (final)
        outb[lane]      = xr0[0];
        outb[lane + 64] = xr1[0];
    }
#pragma unroll
    for (int r = 0; r < 8; ++r) {           // unnormalized local ctx rows
        fma4(p0, er[r], xr0[r]); fma4(p1, er[r], xr1[r]);
        const int t = t0 + wv * 8 + r;
        if (t < T - 1) {
            outb[(size_t)(t + 1) * D4 + lane]      = p0;
            outb[(size_t)(t + 1) * D4 + lane + 64] = p1;
        }
    }
}

// ---------------------------------------------------------------------------
// K2: streaming rescale (no x access).  Per (batch, segment) block:
//   scalar combine from m,q (shuffles) -> sck, Qexcl, invden rows
//   seed_k = sum_{kp<k} sc_kp * V[b,kp,:]   (V is 2 MB, L2-resident)
//   out[b,t+1,:] = (sck * ctx + seed) * invden_t   (read-modify-write, L3-warm)
// ---------------------------------------------------------------------------
__global__ __launch_bounds__(256) void rescale_kernel(
        const float* __restrict__ m_g, const float* __restrict__ q_g,
        const float* __restrict__ V, const float* __restrict__ denloc,
        float* __restrict__ out) {
    const int b = blockIdx.x >> 6, k = blockIdx.x & (NS - 1);
    const int t0 = k * L;
    const int tid = threadIdx.x, lane = tid & 63, wv = tid >> 6;

    float4* outb = (float4*)out + (size_t)b * T * D4;

    // prefetch the 16 ctx float4s this thread will rescale (L3-warm)
    float4 c0[8], c1[8];
#pragma unroll
    for (int r = 0; r < 8; ++r) {
        const int t = t0 + wv * 8 + r;
        if (t < T - 1) {
            c0[r] = outb[(size_t)(t + 1) * D4 + lane];
            c1[r] = outb[(size_t)(t + 1) * D4 + lane + 64];
        }
    }

    __shared__ float accbuf[4][D];
    __shared__ float sc_sh[NS];
    __shared__ float il[L];

    // ---- scalar combine (per-wave redundant) ----
    const float m_i = m_g[b * NS + lane];
    const float q_i = q_g[b * NS + lane];
    float M = m_i;
#pragma unroll
    for (int off = 32; off > 0; off >>= 1) M = fmaxf(M, __shfl_xor(M, off));
    const float sc_i = __expf(m_i - M);
    const float qp = sc_i * q_i;
    float incl = qp;
#pragma unroll
    for (int off = 1; off < 64; off <<= 1) {
        const float t = __shfl_up(incl, off);
        if (lane >= off) incl += t;
    }
    const float Qexcl = __shfl(incl - qp, k);   // sum_{kp<k} sc*q
    const float sck   = __shfl(sc_i, k);
    if (wv == 0) sc_sh[lane] = sc_i;
    __syncthreads();

    // ---- seed: 4 waves split the kp<k range over V ----
    float4 s0 = {0.f, 0.f, 0.f, 0.f}, s1 = {0.f, 0.f, 0.f, 0.f};
    const float4* Vb = (const float4*)V + (size_t)(b * NS) * D4;
    for (int kp = wv; kp < k; kp += 4) {
        const float sc = sc_sh[kp];
        fma4(s0, sc, Vb[(size_t)kp * D4 + lane]);
        fma4(s1, sc, Vb[(size_t)kp * D4 + lane + 64]);
    }
    ((float4*)accbuf[wv])[lane]      = s0;
    ((float4*)accbuf[wv])[lane + 64] = s1;

    if (wv == 0 && lane < L) {              // inverse running denominators
        il[lane] = 1.0f / fmaf(sck, denloc[(size_t)b * T + t0 + lane], Qexcl);
    }
    __syncthreads();

    float4 seed0, seed1;
    {
        const float4 a0 = ((float4*)accbuf[0])[lane];
        const float4 a1 = ((float4*)accbuf[1])[lane];
        const float4 a2 = ((float4*)accbuf[2])[lane];
        const float4 a3 = ((float4*)accbuf[3])[lane];
        seed0.x = (a0.x + a1.x) + (a2.x + a3.x);
        seed0.y = (a0.y + a1.y) + (a2.y + a3.y);
        seed0.z = (a0.z + a1.z) + (a2.z + a3.z);
        seed0.w = (a0.w + a1.w) + (a2.w + a3.w);
        const float4 d0 = ((float4*)accbuf[0])[lane + 64];
        const float4 d1 = ((float4*)accbuf[1])[lane + 64];
        const float4 d2 = ((float4*)accbuf[2])[lane + 64];
        const float4 d3 = ((float4*)accbuf[3])[lane + 64];
        seed1.x = (d0.x + d1.x) + (d2.x + d3.x);
        seed1.y = (d0.y + d1.y) + (d2.y + d3.y);
        seed1.z = (d0.z + d1.z) + (d2.z + d3.z);
        seed1.w = (d0.w + d1.w) + (d2.w + d3.w);
    }

    // ---- stream: out = (sck*ctx + seed) * invden ----
#pragma unroll
    for (int r = 0; r < 8; ++r) {
        const int jj = wv * 8 + r;
        const int t = t0 + jj;
        if (t < T - 1) {
            const float idn = il[jj];
            float4 o0, o1;
            o0.x = fmaf(sck, c0[r].x, seed0.x) * idn;
            o0.y = fmaf(sck, c0[r].y, seed0.y) * idn;
            o0.z = fmaf(sck, c0[r].z, seed0.z) * idn;
            o0.w = fmaf(sck, c0[r].w, seed0.w) * idn;
            o1.x = fmaf(sck, c1[r].x, seed1.x) * idn;
            o1.y = fmaf(sck, c1[r].y, seed1.y) * idn;
            o1.z = fmaf(sck, c1[r].z, seed1.z) * idn;
            o1.w = fmaf(sck, c1[r].w, seed1.w) * idn;
            outb[(size_t)(t + 1) * D4 + lane]      = o0;
            outb[(size_t)(t + 1) * D4 + lane + 64] = o1;
        }
    }
}

// ---------------------------------------------------------------------------
extern "C" void kernel_launch(void* const* d_in, const int* in_sizes, int n_in,
                              void* d_out, int out_size, void* d_ws, size_t ws_size,
                              hipStream_t stream) {
    const float* x    = (const float*)d_in[0];
    const float* w    = (const float*)d_in[1];
    const float* bias = (const float*)d_in[2];
    float* out = (float*)d_out;

    // ws layout (fp32): m[B*NS] | q[B*NS] | denloc[B*T] | V[B*NS*D]
    float* m_g    = (float*)d_ws;
    float* q_g    = m_g    + (size_t)B * NS;
    float* denloc = q_g    + (size_t)B * NS;
    float* V      = denloc + (size_t)B * T;

    seg_scan_kernel<<<B * NS, 256, 0, stream>>>(x, w, bias, m_g, q_g, V, denloc, out);
    rescale_kernel <<<B * NS, 256, 0, stream>>>(m_g, q_g, V, denloc, out);
}